// Round 1
// baseline (2203.607 us; speedup 1.0000x reference)
//
#include <hip/hip_runtime.h>
#include <hip/hip_bf16.h>

#define T_TOK 8192
#define H_DIM 2048
#define I_DIM 4096
#define E_NUM 8
#define MAXROWS 17408   // 16384 + 8*128 padding headroom
#define RB_MAX 136      // MAXROWS / 128

typedef __attribute__((ext_vector_type(8))) __bf16 bf16x8;
typedef __attribute__((ext_vector_type(4))) float f32x4;
typedef __attribute__((ext_vector_type(8))) unsigned short us8;
typedef __attribute__((address_space(3))) unsigned int as3u32;
typedef __attribute__((address_space(1))) unsigned int as1u32;

__device__ __forceinline__ unsigned short f2bf(float f) {
    unsigned u = __float_as_uint(f);
    u += 0x7FFFu + ((u >> 16) & 1u);   // round-to-nearest-even
    return (unsigned short)(u >> 16);
}

// meta layout (ints): [0..7] counts, [8..15] cursors, [16..23] base_row per expert,
// [24] base_row[8], [25] total_rows (128-padded), [26] total_rowblocks, [32..32+RB_MAX) expert_of_rb
__global__ __launch_bounds__(256) void k_init(int* meta, int* row_token) {
    int i = blockIdx.x * 256 + threadIdx.x;
    if (i < 16) meta[i] = 0;
    if (i < MAXROWS) row_token[i] = -1;
}

__global__ __launch_bounds__(256) void k_count(const int* __restrict__ table, int* meta) {
    int i = blockIdx.x * 256 + threadIdx.x;   // over T*K = 16384
    atomicAdd(&meta[table[i]], 1);
}

__global__ void k_prefix(int* meta) {
    if (threadIdx.x == 0 && blockIdx.x == 0) {
        int b = 0;
        for (int e = 0; e < E_NUM; e++) {
            meta[16 + e] = b;
            b += (meta[e] + 127) & ~127;
        }
        meta[24] = b;
        meta[25] = b;
        meta[26] = b >> 7;
        int rb = 0;
        for (int e = 0; e < E_NUM; e++) {
            int nb = ((meta[e] + 127) & ~127) >> 7;
            for (int i = 0; i < nb; i++) meta[32 + rb + i] = e;
            rb += nb;
        }
    }
}

__global__ __launch_bounds__(256) void k_scatter(const int* __restrict__ table,
                                                 const float* __restrict__ rw,
                                                 int* meta, int* row_token, float* row_coef) {
    int i = blockIdx.x * 256 + threadIdx.x;   // over T*K
    int t = i >> 1;
    int e = table[i];
    int pos = meta[16 + e] + atomicAdd(&meta[8 + e], 1);
    row_token[pos] = t;
    row_coef[pos] = rw[i];
}

// one block per permuted row: gather token activations, f32 -> bf16 (zero for pad rows)
__global__ __launch_bounds__(256) void k_gather(const float* __restrict__ x,
                                                const int* __restrict__ row_token,
                                                unsigned short* __restrict__ xp,
                                                const int* __restrict__ meta) {
    int row = blockIdx.x;
    if (row >= meta[25]) return;
    int t = row_token[row];
    int c = threadIdx.x * 8;
    us8 o;
    if (t < 0) {
        for (int k = 0; k < 8; k++) o[k] = 0;
    } else {
        float4 a = *(const float4*)(x + (size_t)t * H_DIM + c);
        float4 b = *(const float4*)(x + (size_t)t * H_DIM + c + 4);
        o[0] = f2bf(a.x); o[1] = f2bf(a.y); o[2] = f2bf(a.z); o[3] = f2bf(a.w);
        o[4] = f2bf(b.x); o[5] = f2bf(b.y); o[6] = f2bf(b.z); o[7] = f2bf(b.w);
    }
    *(us8*)(xp + (size_t)row * H_DIM + c) = o;
}

// f32 -> bf16 bulk conversion, 8 elems/thread, exact grid
__global__ __launch_bounds__(256) void k_cvt(const float* __restrict__ src,
                                             unsigned short* __restrict__ dst, long n) {
    long i = ((long)blockIdx.x * 256 + threadIdx.x) * 8;
    if (i >= n) return;
    float4 a = *(const float4*)(src + i);
    float4 b = *(const float4*)(src + i + 4);
    us8 o;
    o[0] = f2bf(a.x); o[1] = f2bf(a.y); o[2] = f2bf(a.z); o[3] = f2bf(a.w);
    o[4] = f2bf(b.x); o[5] = f2bf(b.y); o[6] = f2bf(b.z); o[7] = f2bf(b.w);
    *(us8*)(dst + i) = o;
}

// GEMM1 + fused SwiGLU. Block tile: 128 rows x 128 gate_up cols = 64 h-cols.
// Per wave (2x2 grid of 64x64): wave cols = 32 gate cols followed by 32 matching up cols,
// so silu(gate)*up pairs acc[i][j] with acc[i][j+2] in the SAME lane.
__global__ __launch_bounds__(256) void k_gemm1(const unsigned short* __restrict__ xp,
                                               const unsigned short* __restrict__ w13b,
                                               unsigned short* __restrict__ hb,
                                               const int* __restrict__ meta) {
    const int rb = blockIdx.y;
    if (rb >= meta[26]) return;
    const int e = meta[32 + rb];
    const int hc0 = blockIdx.x * 64;

    __shared__ unsigned short As[128 * 32];
    __shared__ unsigned short Bs[128 * 32];

    const int tid = threadIdx.x;
    const int lane = tid & 63;
    const int wave = tid >> 6;
    const int wm = wave >> 1, wn = wave & 1;

    const int r0 = tid >> 2;          // staging row 0..63
    const int q8 = (tid & 3) * 8;     // 8-elem chunk within 32-wide K slab
    const size_t row0 = (size_t)rb * 128;

    const unsigned short* aS0 = xp + (row0 + r0) * H_DIM + q8;
    const unsigned short* aS1 = xp + (row0 + 64 + r0) * H_DIM + q8;

    const unsigned short* wb = w13b + (size_t)e * (2 * I_DIM) * H_DIM;
    auto browf = [&](int r) {
        int w = r >> 6, c = r & 63;
        int b = hc0 + w * 32;
        return (c < 32) ? (b + c) : (I_DIM + b + (c - 32));
    };
    const unsigned short* bS0 = wb + (size_t)browf(r0) * H_DIM + q8;
    const unsigned short* bS1 = wb + (size_t)browf(r0 + 64) * H_DIM + q8;

    as3u32* ldsA0 = (as3u32*)As + tid * 4;
    as3u32* ldsA1 = (as3u32*)As + 1024 + tid * 4;
    as3u32* ldsB0 = (as3u32*)Bs + tid * 4;
    as3u32* ldsB1 = (as3u32*)Bs + 1024 + tid * 4;

    f32x4 acc[4][4] = {};
    const int arow = wm * 64 + (lane & 15);
    const int brow = wn * 64 + (lane & 15);
    const int koff = (lane >> 4) * 8;

    for (int k0 = 0; k0 < H_DIM; k0 += 32) {
        __builtin_amdgcn_global_load_lds((const as1u32*)(aS0 + k0), ldsA0, 16, 0, 0);
        __builtin_amdgcn_global_load_lds((const as1u32*)(aS1 + k0), ldsA1, 16, 0, 0);
        __builtin_amdgcn_global_load_lds((const as1u32*)(bS0 + k0), ldsB0, 16, 0, 0);
        __builtin_amdgcn_global_load_lds((const as1u32*)(bS1 + k0), ldsB1, 16, 0, 0);
        __syncthreads();
        bf16x8 af[4], bfr[4];
#pragma unroll
        for (int i = 0; i < 4; i++) af[i] = *(const bf16x8*)&As[(arow + i * 16) * 32 + koff];
#pragma unroll
        for (int j = 0; j < 4; j++) bfr[j] = *(const bf16x8*)&Bs[(brow + j * 16) * 32 + koff];
#pragma unroll
        for (int i = 0; i < 4; i++)
#pragma unroll
            for (int j = 0; j < 4; j++)
                acc[i][j] = __builtin_amdgcn_mfma_f32_16x16x32_bf16(af[i], bfr[j], acc[i][j], 0, 0, 0);
        __syncthreads();
    }

    // epilogue: h = silu(gate) * up, store bf16
    const int colb = hc0 + wn * 32 + (lane & 15);
    const int rowb = rb * 128 + wm * 64 + ((lane >> 4) << 2);
#pragma unroll
    for (int i = 0; i < 4; i++)
#pragma unroll
        for (int j = 0; j < 2; j++)
#pragma unroll
            for (int r = 0; r < 4; r++) {
                float g = acc[i][j][r];
                float u = acc[i][j + 2][r];
                float h = g / (1.0f + __expf(-g)) * u;
                hb[(size_t)(rowb + i * 16 + r) * I_DIM + colb + j * 16] = f2bf(h);
            }
}

// GEMM2: contrib = h @ w2[e]^T, scaled by per-row gate weight, atomicAdd into out
__global__ __launch_bounds__(256) void k_gemm2(const unsigned short* __restrict__ hb,
                                               const unsigned short* __restrict__ w2b,
                                               float* __restrict__ out,
                                               const int* __restrict__ meta,
                                               const int* __restrict__ row_token,
                                               const float* __restrict__ row_coef) {
    const int rb = blockIdx.y;
    if (rb >= meta[26]) return;
    const int e = meta[32 + rb];
    const int n0 = blockIdx.x * 128;

    __shared__ unsigned short As[128 * 32];
    __shared__ unsigned short Bs[128 * 32];

    const int tid = threadIdx.x;
    const int lane = tid & 63;
    const int wave = tid >> 6;
    const int wm = wave >> 1, wn = wave & 1;

    const int r0 = tid >> 2;
    const int q8 = (tid & 3) * 8;
    const size_t row0 = (size_t)rb * 128;

    const unsigned short* aS0 = hb + (row0 + r0) * I_DIM + q8;
    const unsigned short* aS1 = hb + (row0 + 64 + r0) * I_DIM + q8;
    const unsigned short* wb = w2b + (size_t)e * H_DIM * I_DIM;
    const unsigned short* bS0 = wb + (size_t)(n0 + r0) * I_DIM + q8;
    const unsigned short* bS1 = wb + (size_t)(n0 + 64 + r0) * I_DIM + q8;

    as3u32* ldsA0 = (as3u32*)As + tid * 4;
    as3u32* ldsA1 = (as3u32*)As + 1024 + tid * 4;
    as3u32* ldsB0 = (as3u32*)Bs + tid * 4;
    as3u32* ldsB1 = (as3u32*)Bs + 1024 + tid * 4;

    f32x4 acc[4][4] = {};
    const int arow = wm * 64 + (lane & 15);
    const int brow = wn * 64 + (lane & 15);
    const int koff = (lane >> 4) * 8;

    for (int k0 = 0; k0 < I_DIM; k0 += 32) {
        __builtin_amdgcn_global_load_lds((const as1u32*)(aS0 + k0), ldsA0, 16, 0, 0);
        __builtin_amdgcn_global_load_lds((const as1u32*)(aS1 + k0), ldsA1, 16, 0, 0);
        __builtin_amdgcn_global_load_lds((const as1u32*)(bS0 + k0), ldsB0, 16, 0, 0);
        __builtin_amdgcn_global_load_lds((const as1u32*)(bS1 + k0), ldsB1, 16, 0, 0);
        __syncthreads();
        bf16x8 af[4], bfr[4];
#pragma unroll
        for (int i = 0; i < 4; i++) af[i] = *(const bf16x8*)&As[(arow + i * 16) * 32 + koff];
#pragma unroll
        for (int j = 0; j < 4; j++) bfr[j] = *(const bf16x8*)&Bs[(brow + j * 16) * 32 + koff];
#pragma unroll
        for (int i = 0; i < 4; i++)
#pragma unroll
            for (int j = 0; j < 4; j++)
                acc[i][j] = __builtin_amdgcn_mfma_f32_16x16x32_bf16(af[i], bfr[j], acc[i][j], 0, 0, 0);
        __syncthreads();
    }

    const int colb = n0 + wn * 64 + (lane & 15);
    const int rowb = rb * 128 + wm * 64 + ((lane >> 4) << 2);
#pragma unroll
    for (int i = 0; i < 4; i++)
#pragma unroll
        for (int r = 0; r < 4; r++) {
            int row = rowb + i * 16 + r;
            int t = row_token[row];
            if (t < 0) continue;
            float cf = row_coef[row];
            size_t ob = (size_t)t * H_DIM + colb;
#pragma unroll
            for (int j = 0; j < 4; j++)
                atomicAdd(&out[ob + j * 16], cf * acc[i][j][r]);
        }
}

extern "C" void kernel_launch(void* const* d_in, const int* in_sizes, int n_in,
                              void* d_out, int out_size, void* d_ws, size_t ws_size,
                              hipStream_t stream) {
    const float* x     = (const float*)d_in[0];
    const int*   table = (const int*)d_in[1];
    const float* rw    = (const float*)d_in[2];
    const float* w13   = (const float*)d_in[3];
    const float* w2    = (const float*)d_in[4];
    float* out = (float*)d_out;

    char* ws = (char*)d_ws;
    int*   meta      = (int*)ws;                                   // 4 KB
    int*   row_token = (int*)(ws + 4096);                          // 68 KB
    float* row_coef  = (float*)(ws + 4096 + 69632);                // 68 KB
    unsigned short* xp   = (unsigned short*)(ws + 143360);                                   // 71.3 MB
    unsigned short* w13b = (unsigned short*)(ws + 143360 + 71303168ull);                     // 268.4 MB
    unsigned short* w2b  = (unsigned short*)(ws + 143360 + 71303168ull + 268435456ull);      // 134.2 MB
    unsigned short* hb   = (unsigned short*)(ws + 143360 + 71303168ull + 268435456ull + 134217728ull); // 142.6 MB

    k_init<<<68, 256, 0, stream>>>(meta, row_token);
    k_count<<<64, 256, 0, stream>>>(table, meta);
    k_prefix<<<1, 64, 0, stream>>>(meta);
    k_scatter<<<64, 256, 0, stream>>>(table, rw, meta, row_token, row_coef);
    k_gather<<<MAXROWS, 256, 0, stream>>>(x, row_token, xp, meta);
    k_cvt<<<65536, 256, 0, stream>>>(w13, w13b, (long)E_NUM * 2 * I_DIM * H_DIM);
    k_cvt<<<32768, 256, 0, stream>>>(w2, w2b, (long)E_NUM * H_DIM * I_DIM);
    hipMemsetAsync(out, 0, (size_t)T_TOK * H_DIM * sizeof(float), stream);
    k_gemm1<<<dim3(64, RB_MAX), 256, 0, stream>>>(xp, w13b, hb, meta);
    k_gemm2<<<dim3(16, RB_MAX), 256, 0, stream>>>(hb, w2b, out, meta, row_token, row_coef);
}